// Round 4
// baseline (583.796 us; speedup 1.0000x reference)
//
#include <hip/hip_runtime.h>
#include <hip/hip_bf16.h>
#include <math.h>

#define NEGINF (-INFINITY)

typedef float f32x4 __attribute__((ext_vector_type(4)));

__device__ __forceinline__ float wave_max_f(float m) {
#pragma unroll
  for (int d = 32; d > 0; d >>= 1) m = fmaxf(m, __shfl_xor(m, d, 64));
  return m;
}
__device__ __forceinline__ float wave_sum_f(float s) {
#pragma unroll
  for (int d = 32; d > 0; d >>= 1) s += __shfl_xor(s, d, 64);
  return s;
}
__device__ __forceinline__ int wave_sum_i(int s) {
#pragma unroll
  for (int d = 32; d > 0; d >>= 1) s += __shfl_xor(s, d, 64);
  return s;
}

// ---------------------------------------------------------------------------
// Kernel A: per (b,t) row of ctc_out[V]: logsumexp, then gather into packed
// row layout (stride ROWF=LANES*4+8 floats, 16B aligned):
//   row[0 .. LANES*4)  = label lps, quad s -> labels jbase(s)..+3 (clamped)
//   row[LANES*4]       = blank lp
// Row base for (b,t): lp + (b*TPAD + t)*ROWF.
// ---------------------------------------------------------------------------
__global__ __launch_bounds__(256) void kA_lse_gather(
    const float* __restrict__ ctc_out, const int* __restrict__ ctc_label,
    float* __restrict__ lp, int B, int T, int V, int L, int LANES,
    int TPAD, int ROWF)
{
  extern __shared__ float shrow[];  // V floats
  __shared__ float wred[4];
  int row = blockIdx.x;             // b*T + t
  int b = row / T;
  int t = row - b * T;
  int tid = threadIdx.x;
  int w = tid >> 6;
  const float* x = ctc_out + (size_t)row * V;

  float m = NEGINF;
  int nf4 = V >> 2;
  for (int k = tid; k < nf4; k += 256) {
    float4 v = reinterpret_cast<const float4*>(x)[k];
    reinterpret_cast<float4*>(shrow)[k] = v;
    m = fmaxf(m, fmaxf(fmaxf(v.x, v.y), fmaxf(v.z, v.w)));
  }
  for (int k = (nf4 << 2) + tid; k < V; k += 256) {
    float v = x[k]; shrow[k] = v; m = fmaxf(m, v);
  }
  m = wave_max_f(m);
  if ((tid & 63) == 0) wred[w] = m;
  __syncthreads();
  float bm = fmaxf(fmaxf(wred[0], wred[1]), fmaxf(wred[2], wred[3]));
  __syncthreads();

  float s = 0.f;
  for (int k = tid; k < V; k += 256) s += __expf(shrow[k] - bm);
  s = wave_sum_f(s);
  if ((tid & 63) == 0) wred[w] = s;
  __syncthreads();
  float lse = bm + __logf(wred[0] + wred[1] + wred[2] + wred[3]);

  const int* lab = ctc_label + (size_t)b * L;
  float* dst = lp + ((size_t)b * TPAD + t) * ROWF;
  int nq = LANES * 4;
  for (int idx = tid; idx < nq; idx += 256) {
    int sl = idx >> 2, q = idx & 3;
    int jb = ((7 * sl) >> 1) + 1;
    int j = jb + q; if (j > L) j = L;
    int vi = lab[j - 1];
    if ((unsigned)vi >= (unsigned)V) vi = 0;
    dst[idx] = shrow[vi] - lse;
  }
  if (tid == 0) dst[nq] = shrow[0] - lse;
}

// ---------------------------------------------------------------------------
// Kernel B: Viterbi forced alignment, one wave per batch item.
// Lane l owns states 7l..7l+6. lp rows staged global->LDS via
// global_load_lds in 64-row double-buffered segments (fire-and-forget,
// one vmcnt(0) per segment). Consumer reads rows through a 4-deep LDS
// register ring; cross-lane shfl is software-pipelined one iteration deep.
// Transition offsets (2b/state, 14b/lane) go to GLOBAL scratch; backtrace
// chases them with batched speculative reads (7 steps per dependent load).
// ---------------------------------------------------------------------------
__global__ __launch_bounds__(64, 1) void kB_viterbi(
    const float* __restrict__ lp, const int* __restrict__ ctc_label,
    unsigned short* __restrict__ offg, float* __restrict__ ali,
    int B, int T, int L, int TPAD, int ROWF)
{
  extern __shared__ float smemf[];   // 2 * 64 * ROWF floats
  const int N = 2 * L + 1;
  const int LANES = (N + 6) / 7;
  float* hA = smemf;
  float* hB = smemf + 64 * ROWF;

  int b = blockIdx.x;
  int lane = threadIdx.x;
  const float* lpb = lp + (size_t)b * TPAD * ROWF;
  unsigned short* offb = offg + (size_t)b * (T - 1) * LANES;
  const int* lab = ctc_label + (size_t)b * L;
  int qlane = (lane < LANES) ? lane : (LANES - 1);
  int blkoff = LANES * 4;            // blank offset within row

  int i0 = lane * 7;
  float a[7];
  int twv[7];
  int tlo[7];
  unsigned rng[7];
#pragma unroll
  for (int s = 0; s < 7; ++s) {
    int i = i0 + s;
    bool valid = (i < N);
    bool odd = (i & 1) != 0;
    int li = (i - 1) >> 1;
    int myl = (odd && valid) ? lab[li] : 0;
    int pl  = (odd && valid && i >= 3) ? lab[li - 1] : -1;
    twv[s] = ((!odd) || (i == 1) || (myl == pl)) ? 1 : 0;
    if (valid) {
      tlo[s] = (i + 1) >> 1;                 // t >= ceil(i/2)
      int thi = T - L + (i >> 1);            // t <= T-L+floor(i/2)
      rng[s] = (unsigned)(thi - tlo[s]);
    } else {
      tlo[s] = T + 2;
      rng[s] = 0u;
    }
  }

  // t=0 init: only states 0,1 get lp, rest -inf.
  {
    f32x4 q00 = reinterpret_cast<const f32x4*>(lpb)[qlane];
    float bl00 = lpb[blkoff];
#pragma unroll
    for (int s = 0; s < 7; ++s) {
      int i = i0 + s;
      a[s] = (i == 0) ? bl00 : ((i == 1) ? q00.x : NEGINF);
    }
  }

  int NDMA = ROWF / 4;               // 1KB instructions per 64-row segment
  int CH = NDMA / 4;                 // chunk size (issued 4x per segment)

  // DMA one chunk of a segment: rows [row0, row0+64) -> dsthalf
#define DMA_CHUNK(row0, c, dsthalf)                                           \
  {                                                                           \
    const float* gsrc_ = lpb + (size_t)(row0) * ROWF;                         \
    int k0_ = (c) * CH, k1_ = (c) * CH + CH;                                  \
    for (int kk_ = k0_; kk_ < k1_; ++kk_) {                                   \
      __builtin_amdgcn_global_load_lds(                                       \
          (const unsigned int*)(gsrc_ + (size_t)kk_ * 256 + lane * 4),        \
          (unsigned int*)((dsthalf) + (size_t)kk_ * 256), 16, 0, 0);          \
    }                                                                         \
  }

#define RING_LOAD(half_, u_, slot_)                                           \
  {                                                                           \
    const float* rb_ = (half_) + (size_t)(u_) * ROWF;                         \
    rq[slot_] = *reinterpret_cast<const f32x4*>(rb_ + qlane * 4);             \
    rbl[slot_] = rb_[blkoff];                                                 \
  }

#define STEP_F(s, P0, P1, P2, OCS, ND, OD)                                    \
  {                                                                           \
    bool c01 = (P0) > (P1);                                                   \
    float m01 = c01 ? (P0) : (P1);                                            \
    bool take3 = (twv[s] == 0) && !(m01 > (P2));                              \
    float asel = take3 ? (P2) : m01;                                          \
    OD = take3 ? 2u : (c01 ? 0u : 1u);                                        \
    float lps = (((lane + (s)) & 1) ? (OCS) : blc);                           \
    ND = asel + lps;                                                          \
  }

#define STEP_S(s, P0, P1, P2, OCS, ND, OD)                                    \
  {                                                                           \
    STEP_F(s, P0, P1, P2, OCS, ND, OD)                                        \
    bool feas = (unsigned)(tt - tlo[s]) <= rng[s];                            \
    ND = feas ? ND : NEGINF;                                                  \
  }

  // One DP step. RU = ring slot (compile-time), UU = row index in segment.
  // States 5,6 first (no cross-lane dep) -> issue next iteration's shfl
  // early -> states 0..4 with previous shfl results.
#define BODY(RU, STEPM, UU)                                                   \
  {                                                                           \
    int u_ = (UU);                                                            \
    int tt = tt0 + u_;                                                        \
    float blc = rbl[RU];                                                      \
    f32x4 oc = rq[RU];                                                        \
    if (u_ + 4 < 64) { RING_LOAD(half, u_ + 4, RU) }                          \
    float n0, n1, n2, n3, n4, n5, n6;                                         \
    unsigned o0, o1, o2, o3, o4, o5, o6;                                      \
    STEPM(5, a[5], a[4], a[3], oc.z, n5, o5)                                  \
    STEPM(6, a[6], a[5], a[4], oc.w, n6, o6)                                  \
    float t6n = __shfl_up(n6, 1, 64);                                         \
    float t5n = __shfl_up(n5, 1, 64);                                         \
    STEPM(0, a[0], t6, t5, oc.x, n0, o0)                                      \
    STEPM(1, a[1], a[0], t6, oc.x, n1, o1)                                    \
    STEPM(2, a[2], a[1], a[0], oc.y, n2, o2)                                  \
    STEPM(3, a[3], a[2], a[1], oc.y, n3, o3)                                  \
    STEPM(4, a[4], a[3], a[2], oc.z, n4, o4)                                  \
    unsigned pack = o0 | (o1 << 2) | (o2 << 4) | (o3 << 6) | (o4 << 8) |      \
                    (o5 << 10) | (o6 << 12);                                  \
    if (lane < LANES)                                                         \
      offb[(size_t)(tt - 1) * LANES + lane] = (unsigned short)pack;           \
    a[0] = n0; a[1] = n1; a[2] = n2; a[3] = n3; a[4] = n4; a[5] = n5;         \
    a[6] = n6;                                                                \
    t6 = (lane == 0) ? NEGINF : t6n;                                          \
    t5 = (lane == 0) ? NEGINF : t5n;                                          \
  }

  // Prologue: DMA segment 0 (rows tt=1..64) into hA, drain.
  DMA_CHUNK(1, 0, hA)
  DMA_CHUNK(1, 1, hA)
  DMA_CHUNK(1, 2, hA)
  DMA_CHUNK(1, 3, hA)
  asm volatile("s_waitcnt vmcnt(0)");
  __builtin_amdgcn_sched_barrier(0);

  // Initial shfl (t=0 state) for the first body.
  float t6 = __shfl_up(a[6], 1, 64);
  float t5 = __shfl_up(a[5], 1, 64);
  if (lane == 0) { t6 = NEGINF; t5 = NEGINF; }

  f32x4 rq[4];
  float rbl[4];

  int NSEG = (T - 1 + 63) / 64;
  for (int sg = 0; sg < NSEG; ++sg) {
    int tt0 = 1 + 64 * sg;
    float* half  = (sg & 1) ? hB : hA;
    float* nhalf = (sg & 1) ? hA : hB;
    RING_LOAD(half, 0, 0)
    RING_LOAD(half, 1, 1)
    RING_LOAD(half, 2, 2)
    RING_LOAD(half, 3, 3)
    for (int jj = 0; jj < 8; ++jj) {
      if (((jj & 1) == 0) && (sg + 1 < NSEG)) {
        DMA_CHUNK(tt0 + 64, (jj >> 1), nhalf)
      }
      int jj8 = jj * 8;
      int ttb = tt0 + jj8;
      if (ttb >= L && (ttb + 7) <= (T - L) && (ttb + 7) <= (T - 1)) {
        BODY(0, STEP_F, jj8 + 0)
        BODY(1, STEP_F, jj8 + 1)
        BODY(2, STEP_F, jj8 + 2)
        BODY(3, STEP_F, jj8 + 3)
        BODY(0, STEP_F, jj8 + 4)
        BODY(1, STEP_F, jj8 + 5)
        BODY(2, STEP_F, jj8 + 6)
        BODY(3, STEP_F, jj8 + 7)
      } else {
        int rem = T - ttb;   // bodies to run in this 8-block (trailing skip)
        if (0 < rem) BODY(0, STEP_S, jj8 + 0)
        if (1 < rem) BODY(1, STEP_S, jj8 + 1)
        if (2 < rem) BODY(2, STEP_S, jj8 + 2)
        if (3 < rem) BODY(3, STEP_S, jj8 + 3)
        if (4 < rem) BODY(0, STEP_S, jj8 + 4)
        if (5 < rem) BODY(1, STEP_S, jj8 + 5)
        if (6 < rem) BODY(2, STEP_S, jj8 + 6)
        if (7 < rem) BODY(3, STEP_S, jj8 + 7)
      }
    }
    asm volatile("s_waitcnt vmcnt(0)");
    __builtin_amdgcn_sched_barrier(0);
  }
#undef BODY
#undef STEP_S
#undef STEP_F
#undef RING_LOAD
#undef DMA_CHUNK

  // Final-state values via lane shuffle (state i -> lane i/7, slot i%7).
  int iN1 = N - 1, iN2 = N - 2;
  auto pick = [&](int sIdx) {
    float r = a[0];
    r = (sIdx == 1) ? a[1] : r;
    r = (sIdx == 2) ? a[2] : r;
    r = (sIdx == 3) ? a[3] : r;
    r = (sIdx == 4) ? a[4] : r;
    r = (sIdx == 5) ? a[5] : r;
    r = (sIdx == 6) ? a[6] : r;
    return r;
  };
  float vlast = __shfl(pick(iN1 % 7), iN1 / 7, 64);
  float vprev = __shfl(pick(iN2 % 7), iN2 / 7, 64);
  bool use_last = vlast > vprev;
  int pre = use_last ? iN1 : iN2;

  float al[4] = {0.f, 0.f, 0.f, 0.f};
  {
    int lbl = L - 1; int rr = lbl >> 6, ln = lbl & 63;
#pragma unroll
    for (int r = 0; r < 4; ++r)
      if (!use_last && rr == r && lane == ln) al[r] = (float)T;
  }

  // Backtrace: batches of K<=7 steps, speculative candidate-group reads.
  int t = T - 1;
  int g = pre / 7, mm = pre - g * 7;
  while (t >= 1) {
    int K = (t < 7) ? t : 7;
    int pcur = g * 7 + mm;
    int gmax = g;
    unsigned short w0v = offb[(size_t)(t - 1) * LANES + g];
    unsigned short cw[7][3];
    int gmn[7];
#pragma unroll
    for (int j = 1; j < 7; ++j) {
      if (j < K) {
        int lo = pcur - 2 * j; if (lo < 0) lo = 0;
        int gm = lo / 7;
        gmn[j] = gm;
#pragma unroll
        for (int r = 0; r < 3; ++r) {
          int gg = gm + r; if (gg > gmax) gg = gmax;
          cw[j][r] = offb[(size_t)(t - 1 - j) * LANES + gg];
        }
      }
    }
#pragma unroll
    for (int j = 0; j < 7; ++j) {
      if (j < K) {
        unsigned w;
        if (j == 0) {
          w = w0v;
        } else {
          int gi = g - gmn[j];
          unsigned wa = cw[j][0], wb = cw[j][1], wc2 = cw[j][2];
          w = (gi == 0) ? wa : ((gi == 1) ? wb : wc2);
        }
        unsigned off = (w >> (2 * mm)) & 3u;
        mm -= (int)off;
        bool bor = mm < 0;
        g = bor ? (g - 1) : g;
        mm = bor ? (mm + 7) : mm;
        int cur = g * 7 + mm;
        if (cur & 1) {
          int lbl = cur >> 1;
          int rr = lbl >> 6, ln = lbl & 63;
#pragma unroll
          for (int r = 0; r < 4; ++r)
            if (rr == r && lane == ln) al[r] = (float)(t - j);
        }
      }
    }
    t -= K;
  }

#pragma unroll
  for (int r = 0; r < 4; ++r) {
    int l = lane + 64 * r;
    if (l < L) ali[(size_t)b * L + l] = al[r];
  }
}

// ---------------------------------------------------------------------------
// Kernel C: one wave per (b,layer,o<L) row: dot(ali_out_row, pos) - ali,
// masked, squared; 4 rows/block -> per-block partial sum.
// ---------------------------------------------------------------------------
__global__ __launch_bounds__(256) void kC_rows(
    const float* __restrict__ ali_out, const float* __restrict__ ali,
    const int* __restrict__ ali_beg, float* __restrict__ partials,
    int B, int layers, int L, int T)
{
  __shared__ float ps[4];
  int wid = threadIdx.x >> 6, lane = threadIdx.x & 63;
  int row = blockIdx.x * 4 + wid;
  int nrows = B * layers * L;
  float val = 0.f;
  if (row < nrows) {
    int o = row % L;
    int bl = row / L;
    int layer = bl % layers;
    int b = bl / layers;
    const float* x = ali_out + ((size_t)(b * layers + layer) * (L + 1) + o) * T;
    float s = 0.f;
    if ((T & 3) == 0) {
      int nf4 = T >> 2;
      for (int k = lane; k < nf4; k += 64) {
        float4 v = reinterpret_cast<const float4*>(x)[k];
        float base = (float)(4 * k);
        s += v.x * (base + 1.f) + v.y * (base + 2.f) +
             v.z * (base + 3.f) + v.w * (base + 4.f);
      }
    } else {
      for (int k = lane; k < T; k += 64) s += x[k] * (float)(k + 1);
    }
    s = wave_sum_f(s);
    int cnt = 0;
    for (int l = lane; l < L; l += 64)
      cnt += (ali_beg[(size_t)b * L + l] != -1) ? 1 : 0;
    cnt = wave_sum_i(cnt);
    if (lane == 0) {
      float lat = (o >= cnt) ? 0.f : (s - ali[(size_t)b * L + o]);
      val = lat * lat;
    }
  }
  if (lane == 0) ps[wid] = val;
  __syncthreads();
  if (threadIdx.x == 0) partials[blockIdx.x] = ps[0] + ps[1] + ps[2] + ps[3];
}

// ---------------------------------------------------------------------------
// Kernel D: reduce partials, compute total = layers * sum(ylen), write scalar.
// ---------------------------------------------------------------------------
__global__ __launch_bounds__(256) void kD_final(
    const float* __restrict__ partials, int nparts,
    const int* __restrict__ ali_beg, int BL, int layers, int T,
    float* __restrict__ out)
{
  __shared__ float wred[4];
  __shared__ int wcnt[4];
  int tid = threadIdx.x, w = tid >> 6;
  float s = 0.f;
  for (int k = tid; k < nparts; k += 256) s += partials[k];
  s = wave_sum_f(s);
  int c = 0;
  for (int k = tid; k < BL; k += 256) c += (ali_beg[k] != -1) ? 1 : 0;
  c = wave_sum_i(c);
  if ((tid & 63) == 0) { wred[w] = s; wcnt[w] = c; }
  __syncthreads();
  if (tid == 0) {
    float ss = wred[0] + wred[1] + wred[2] + wred[3];
    float total = (float)(wcnt[0] + wcnt[1] + wcnt[2] + wcnt[3]) * (float)layers;
    out[0] = ss / total / (float)T;
  }
}

extern "C" void kernel_launch(void* const* d_in, const int* in_sizes, int n_in,
                              void* d_out, int out_size, void* d_ws, size_t ws_size,
                              hipStream_t stream)
{
  const float* ali_out   = (const float*)d_in[0];
  const int*   ali_beg   = (const int*)d_in[1];
  // d_in[2] ali_end, d_in[3] enc_mask, d_in[6] ctc_len: unused by reference math
  const float* ctc_out   = (const float*)d_in[4];
  const int*   ctc_label = (const int*)d_in[5];

  int B = in_sizes[6];
  int L = in_sizes[1] / B;
  int T = in_sizes[3] / B;
  int V = (int)((long long)in_sizes[4] / ((long long)B * T));
  int layers = (int)((long long)in_sizes[0] / ((long long)B * (L + 1) * T));

  int N = 2 * L + 1;
  int LANES = (N + 6) / 7;           // 58
  int ROWF = LANES * 4 + 8;          // 240 floats (960 B, 16B aligned)
  int TPAD = T + 64;                 // DMA over-read pad

  // workspace layout
  float* lp = (float*)d_ws;                              // B*TPAD*ROWF floats
  float* ali = lp + (size_t)B * TPAD * ROWF;             // B*L
  float* partials = ali + (size_t)B * L;                 // gridC
  int nrows = B * layers * L;
  int gridC = (nrows + 3) / 4;
  unsigned short* offg = (unsigned short*)(partials + gridC);  // B*(T-1)*LANES

  // A: logsumexp + gather into packed rows
  size_t shA = (size_t)V * sizeof(float);
  hipLaunchKernelGGL(kA_lse_gather, dim3(B * T), dim3(256), shA, stream,
                     ctc_out, ctc_label, lp, B, T, V, L, LANES, TPAD, ROWF);

  // B: Viterbi forward + backtrace (one wave per batch item)
  size_t shB = (size_t)2 * 64 * ROWF * sizeof(float);    // 122880 B
  hipFuncSetAttribute(reinterpret_cast<const void*>(kB_viterbi),
                      hipFuncAttributeMaxDynamicSharedMemorySize, (int)shB);
  hipLaunchKernelGGL(kB_viterbi, dim3(B), dim3(64), shB, stream,
                     lp, ctc_label, offg, ali, B, T, L, TPAD, ROWF);

  // C: expected-position rows + squared residual partials
  hipLaunchKernelGGL(kC_rows, dim3(gridC), dim3(256), 0, stream,
                     ali_out, ali, ali_beg, partials, B, layers, L, T);

  // D: finalize scalar
  hipLaunchKernelGGL(kD_final, dim3(1), dim3(256), 0, stream,
                     partials, gridC, ali_beg, B * L, layers, T, (float*)d_out);
}

// Round 5
// 574.727 us; speedup vs baseline: 1.0158x; 1.0158x over previous
//
#include <hip/hip_runtime.h>
#include <hip/hip_bf16.h>
#include <math.h>

#define NEGINF (-INFINITY)

typedef float f32x4 __attribute__((ext_vector_type(4)));

__device__ __forceinline__ float wave_max_f(float m) {
#pragma unroll
  for (int d = 32; d > 0; d >>= 1) m = fmaxf(m, __shfl_xor(m, d, 64));
  return m;
}
__device__ __forceinline__ float wave_sum_f(float s) {
#pragma unroll
  for (int d = 32; d > 0; d >>= 1) s += __shfl_xor(s, d, 64);
  return s;
}
__device__ __forceinline__ int wave_sum_i(int s) {
#pragma unroll
  for (int d = 32; d > 0; d >>= 1) s += __shfl_xor(s, d, 64);
  return s;
}

// Whole-wave shift-right-by-1 via DPP (pure VALU, no LDS/lgkmcnt).
// Lane l receives lane l-1's value; lane 0 gets 0 (overridden by caller).
__device__ __forceinline__ float dpp_wave_shr1(float x) {
  int r = __builtin_amdgcn_mov_dpp(__float_as_int(x), 0x138, 0xf, 0xf, true);
  return __int_as_float(r);
}

// ---------------------------------------------------------------------------
// Kernel A: per (b,t) row of ctc_out[V]: logsumexp, then gather into packed
// row layout (stride ROWF=LANES*4+8 floats, 16B aligned):
//   row[0 .. LANES*4)  = label lps, quad s -> labels jbase(s)..+3 (clamped)
//   row[LANES*4]       = blank lp
// Row base for (b,t): lp + (b*TPAD + t)*ROWF.
// ---------------------------------------------------------------------------
__global__ __launch_bounds__(256) void kA_lse_gather(
    const float* __restrict__ ctc_out, const int* __restrict__ ctc_label,
    float* __restrict__ lp, int B, int T, int V, int L, int LANES,
    int TPAD, int ROWF)
{
  extern __shared__ float shrow[];  // V floats
  __shared__ float wred[4];
  int row = blockIdx.x;             // b*T + t
  int b = row / T;
  int t = row - b * T;
  int tid = threadIdx.x;
  int w = tid >> 6;
  const float* x = ctc_out + (size_t)row * V;

  float m = NEGINF;
  int nf4 = V >> 2;
  for (int k = tid; k < nf4; k += 256) {
    float4 v = reinterpret_cast<const float4*>(x)[k];
    reinterpret_cast<float4*>(shrow)[k] = v;
    m = fmaxf(m, fmaxf(fmaxf(v.x, v.y), fmaxf(v.z, v.w)));
  }
  for (int k = (nf4 << 2) + tid; k < V; k += 256) {
    float v = x[k]; shrow[k] = v; m = fmaxf(m, v);
  }
  m = wave_max_f(m);
  if ((tid & 63) == 0) wred[w] = m;
  __syncthreads();
  float bm = fmaxf(fmaxf(wred[0], wred[1]), fmaxf(wred[2], wred[3]));
  __syncthreads();

  float s = 0.f;
  for (int k = tid; k < V; k += 256) s += __expf(shrow[k] - bm);
  s = wave_sum_f(s);
  if ((tid & 63) == 0) wred[w] = s;
  __syncthreads();
  float lse = bm + __logf(wred[0] + wred[1] + wred[2] + wred[3]);

  const int* lab = ctc_label + (size_t)b * L;
  float* dst = lp + ((size_t)b * TPAD + t) * ROWF;
  int nq = LANES * 4;
  for (int idx = tid; idx < nq; idx += 256) {
    int sl = idx >> 2, q = idx & 3;
    int jb = ((7 * sl) >> 1) + 1;
    int j = jb + q; if (j > L) j = L;
    int vi = lab[j - 1];
    if ((unsigned)vi >= (unsigned)V) vi = 0;
    dst[idx] = shrow[vi] - lse;
  }
  if (tid == 0) dst[nq] = shrow[0] - lse;
}

// ---------------------------------------------------------------------------
// Kernel B: Viterbi forced alignment, one wave per batch item.
// Lane l owns states 7l..7l+6. lp rows staged global->LDS via
// global_load_lds, 64-row double-buffered segments: the full 60-instruction
// DMA burst for segment sg+1 is issued at the START of segment sg (64 bodies
// of slack before its vmcnt(0) drain). Inner body: 2 ds_read (4-deep ring)
// + ~66 VALU + 1 fire-and-forget global store. Cross-lane exchange uses DPP
// wave_shr1 (pure VALU) instead of ds_bpermute - nothing in the body waits
// on LDS except the 4-body-slack ring reads.
// Transition offsets (2b/state, 14b/lane) go to GLOBAL scratch; backtrace
// chases them with batched speculative reads (7 steps per dependent load).
// ---------------------------------------------------------------------------
__global__ __launch_bounds__(64, 1) void kB_viterbi(
    const float* __restrict__ lp, const int* __restrict__ ctc_label,
    unsigned short* __restrict__ offg, float* __restrict__ ali,
    int B, int T, int L, int TPAD, int ROWF)
{
  extern __shared__ float smemf[];   // 2 * 64 * ROWF floats
  const int N = 2 * L + 1;
  const int LANES = (N + 6) / 7;
  float* hA = smemf;
  float* hB = smemf + 64 * ROWF;

  int b = blockIdx.x;
  int lane = threadIdx.x;
  const float* lpb = lp + (size_t)b * TPAD * ROWF;
  unsigned short* offb = offg + (size_t)b * (T - 1) * LANES;
  const int* lab = ctc_label + (size_t)b * L;
  int qlane = (lane < LANES) ? lane : (LANES - 1);
  int blkoff = LANES * 4;            // blank offset within row
  int NDMA = (ROWF * 64) / 256;      // 1KB DMA instructions per segment

  int i0 = lane * 7;
  float a[7];
  int twv[7];
  int tlo[7];
  unsigned rng[7];
#pragma unroll
  for (int s = 0; s < 7; ++s) {
    int i = i0 + s;
    bool valid = (i < N);
    bool odd = (i & 1) != 0;
    int li = (i - 1) >> 1;
    int myl = (odd && valid) ? lab[li] : 0;
    int pl  = (odd && valid && i >= 3) ? lab[li - 1] : -1;
    twv[s] = ((!odd) || (i == 1) || (myl == pl)) ? 1 : 0;
    if (valid) {
      tlo[s] = (i + 1) >> 1;                 // t >= ceil(i/2)
      int thi = T - L + (i >> 1);            // t <= T-L+floor(i/2)
      rng[s] = (unsigned)(thi - tlo[s]);
    } else {
      tlo[s] = T + 2;
      rng[s] = 0u;
    }
  }

  // t=0 init: only states 0,1 get lp, rest -inf.
  {
    f32x4 q00 = reinterpret_cast<const f32x4*>(lpb)[qlane];
    float bl00 = lpb[blkoff];
#pragma unroll
    for (int s = 0; s < 7; ++s) {
      int i = i0 + s;
      a[s] = (i == 0) ? bl00 : ((i == 1) ? q00.x : NEGINF);
    }
  }

  // DMA one whole 64-row segment starting at row0 into dsthalf.
#define DMA_SEG(row0, dsthalf)                                                \
  {                                                                           \
    const float* gsrc_ = lpb + (size_t)(row0) * ROWF;                         \
    for (int kk_ = 0; kk_ < NDMA; ++kk_) {                                    \
      __builtin_amdgcn_global_load_lds(                                       \
          (const unsigned int*)(gsrc_ + (size_t)kk_ * 256 + lane * 4),        \
          (unsigned int*)((dsthalf) + (size_t)kk_ * 256), 16, 0, 0);          \
    }                                                                         \
  }

#define RING_LOAD(half_, u_, slot_)                                           \
  {                                                                           \
    const float* rb_ = (half_) + (size_t)(u_) * ROWF;                         \
    rq[slot_] = *reinterpret_cast<const f32x4*>(rb_ + qlane * 4);             \
    rbl[slot_] = rb_[blkoff];                                                 \
  }

#define STEP_F(s, P0, P1, P2, OCS, ND, OD)                                    \
  {                                                                           \
    bool c01 = (P0) > (P1);                                                   \
    float m01 = c01 ? (P0) : (P1);                                            \
    bool take3 = (twv[s] == 0) && !(m01 > (P2));                              \
    float asel = take3 ? (P2) : m01;                                          \
    OD = take3 ? 2u : (c01 ? 0u : 1u);                                        \
    float lps = (((lane + (s)) & 1) ? (OCS) : blc);                           \
    ND = asel + lps;                                                          \
  }

#define STEP_S(s, P0, P1, P2, OCS, ND, OD)                                    \
  {                                                                           \
    STEP_F(s, P0, P1, P2, OCS, ND, OD)                                        \
    bool feas = (unsigned)(tt - tlo[s]) <= rng[s];                            \
    ND = feas ? ND : NEGINF;                                                  \
  }

  // One DP step. RU = ring slot (compile-time), UU = row index in segment.
  // States 5,6 first (lane-local) -> DPP shift (VALU) -> states 0..4 with
  // the PREVIOUS iteration's shifted values.
#define BODY(RU, STEPM, UU)                                                   \
  {                                                                           \
    int u_ = (UU);                                                            \
    int tt = tt0 + u_;                                                        \
    float blc = rbl[RU];                                                      \
    f32x4 oc = rq[RU];                                                        \
    if (u_ + 4 < 64) { RING_LOAD(half, u_ + 4, RU) }                          \
    float n0, n1, n2, n3, n4, n5, n6;                                         \
    unsigned o0, o1, o2, o3, o4, o5, o6;                                      \
    STEPM(5, a[5], a[4], a[3], oc.z, n5, o5)                                  \
    STEPM(6, a[6], a[5], a[4], oc.w, n6, o6)                                  \
    float t6n = dpp_wave_shr1(n6);                                            \
    float t5n = dpp_wave_shr1(n5);                                            \
    STEPM(0, a[0], t6, t5, oc.x, n0, o0)                                      \
    STEPM(1, a[1], a[0], t6, oc.x, n1, o1)                                    \
    STEPM(2, a[2], a[1], a[0], oc.y, n2, o2)                                  \
    STEPM(3, a[3], a[2], a[1], oc.y, n3, o3)                                  \
    STEPM(4, a[4], a[3], a[2], oc.z, n4, o4)                                  \
    unsigned pack = o0 | (o1 << 2) | (o2 << 4) | (o3 << 6) | (o4 << 8) |      \
                    (o5 << 10) | (o6 << 12);                                  \
    if (lane < LANES)                                                         \
      offb[(size_t)(tt - 1) * LANES + lane] = (unsigned short)pack;           \
    a[0] = n0; a[1] = n1; a[2] = n2; a[3] = n3; a[4] = n4; a[5] = n5;         \
    a[6] = n6;                                                                \
    t6 = (lane == 0) ? NEGINF : t6n;                                          \
    t5 = (lane == 0) ? NEGINF : t5n;                                          \
  }

  // Prologue: DMA segment 0 (rows tt=1..64) into hA, drain.
  DMA_SEG(1, hA)
  asm volatile("s_waitcnt vmcnt(0)");
  __builtin_amdgcn_sched_barrier(0);

  // Initial shifted values (t=0 state) for the first body (outside loop,
  // latency irrelevant).
  float t6 = __shfl_up(a[6], 1, 64);
  float t5 = __shfl_up(a[5], 1, 64);
  if (lane == 0) { t6 = NEGINF; t5 = NEGINF; }

  f32x4 rq[4];
  float rbl[4];

  int NSEG = (T - 1 + 63) / 64;
  for (int sg = 0; sg < NSEG; ++sg) {
    int tt0 = 1 + 64 * sg;
    float* half  = (sg & 1) ? hB : hA;
    float* nhalf = (sg & 1) ? hA : hB;
    // Issue next segment's whole DMA burst now: 64 bodies of slack before
    // its drain at the end of this segment.
    if (sg + 1 < NSEG) { DMA_SEG(tt0 + 64, nhalf) }
    RING_LOAD(half, 0, 0)
    RING_LOAD(half, 1, 1)
    RING_LOAD(half, 2, 2)
    RING_LOAD(half, 3, 3)
    for (int jj = 0; jj < 8; ++jj) {
      int jj8 = jj * 8;
      int ttb = tt0 + jj8;
      if (ttb >= L && (ttb + 7) <= (T - L) && (ttb + 7) <= (T - 1)) {
        BODY(0, STEP_F, jj8 + 0)
        BODY(1, STEP_F, jj8 + 1)
        BODY(2, STEP_F, jj8 + 2)
        BODY(3, STEP_F, jj8 + 3)
        BODY(0, STEP_F, jj8 + 4)
        BODY(1, STEP_F, jj8 + 5)
        BODY(2, STEP_F, jj8 + 6)
        BODY(3, STEP_F, jj8 + 7)
      } else {
        int rem = T - ttb;   // bodies to run in this 8-block (trailing skip)
        if (0 < rem) BODY(0, STEP_S, jj8 + 0)
        if (1 < rem) BODY(1, STEP_S, jj8 + 1)
        if (2 < rem) BODY(2, STEP_S, jj8 + 2)
        if (3 < rem) BODY(3, STEP_S, jj8 + 3)
        if (4 < rem) BODY(0, STEP_S, jj8 + 4)
        if (5 < rem) BODY(1, STEP_S, jj8 + 5)
        if (6 < rem) BODY(2, STEP_S, jj8 + 6)
        if (7 < rem) BODY(3, STEP_S, jj8 + 7)
      }
    }
    asm volatile("s_waitcnt vmcnt(0)");
    __builtin_amdgcn_sched_barrier(0);
  }
#undef BODY
#undef STEP_S
#undef STEP_F
#undef RING_LOAD
#undef DMA_SEG

  // Final-state values via lane shuffle (state i -> lane i/7, slot i%7).
  int iN1 = N - 1, iN2 = N - 2;
  auto pick = [&](int sIdx) {
    float r = a[0];
    r = (sIdx == 1) ? a[1] : r;
    r = (sIdx == 2) ? a[2] : r;
    r = (sIdx == 3) ? a[3] : r;
    r = (sIdx == 4) ? a[4] : r;
    r = (sIdx == 5) ? a[5] : r;
    r = (sIdx == 6) ? a[6] : r;
    return r;
  };
  float vlast = __shfl(pick(iN1 % 7), iN1 / 7, 64);
  float vprev = __shfl(pick(iN2 % 7), iN2 / 7, 64);
  bool use_last = vlast > vprev;
  int pre = use_last ? iN1 : iN2;

  float al[4] = {0.f, 0.f, 0.f, 0.f};
  {
    int lbl = L - 1; int rr = lbl >> 6, ln = lbl & 63;
#pragma unroll
    for (int r = 0; r < 4; ++r)
      if (!use_last && rr == r && lane == ln) al[r] = (float)T;
  }

  // Backtrace: batches of K<=7 steps, speculative candidate-group reads.
  int t = T - 1;
  int g = pre / 7, mm = pre - g * 7;
  while (t >= 1) {
    int K = (t < 7) ? t : 7;
    int pcur = g * 7 + mm;
    int gmax = g;
    unsigned short w0v = offb[(size_t)(t - 1) * LANES + g];
    unsigned short cw[7][3];
    int gmn[7];
#pragma unroll
    for (int j = 1; j < 7; ++j) {
      if (j < K) {
        int lo = pcur - 2 * j; if (lo < 0) lo = 0;
        int gm = lo / 7;
        gmn[j] = gm;
#pragma unroll
        for (int r = 0; r < 3; ++r) {
          int gg = gm + r; if (gg > gmax) gg = gmax;
          cw[j][r] = offb[(size_t)(t - 1 - j) * LANES + gg];
        }
      }
    }
#pragma unroll
    for (int j = 0; j < 7; ++j) {
      if (j < K) {
        unsigned w;
        if (j == 0) {
          w = w0v;
        } else {
          int gi = g - gmn[j];
          unsigned wa = cw[j][0], wb = cw[j][1], wc2 = cw[j][2];
          w = (gi == 0) ? wa : ((gi == 1) ? wb : wc2);
        }
        unsigned off = (w >> (2 * mm)) & 3u;
        mm -= (int)off;
        bool bor = mm < 0;
        g = bor ? (g - 1) : g;
        mm = bor ? (mm + 7) : mm;
        int cur = g * 7 + mm;
        if (cur & 1) {
          int lbl = cur >> 1;
          int rr = lbl >> 6, ln = lbl & 63;
#pragma unroll
          for (int r = 0; r < 4; ++r)
            if (rr == r && lane == ln) al[r] = (float)(t - j);
        }
      }
    }
    t -= K;
  }

#pragma unroll
  for (int r = 0; r < 4; ++r) {
    int l = lane + 64 * r;
    if (l < L) ali[(size_t)b * L + l] = al[r];
  }
}

// ---------------------------------------------------------------------------
// Kernel C: one wave per (b,layer,o<L) row: dot(ali_out_row, pos) - ali,
// masked, squared; 4 rows/block -> per-block partial sum.
// ---------------------------------------------------------------------------
__global__ __launch_bounds__(256) void kC_rows(
    const float* __restrict__ ali_out, const float* __restrict__ ali,
    const int* __restrict__ ali_beg, float* __restrict__ partials,
    int B, int layers, int L, int T)
{
  __shared__ float ps[4];
  int wid = threadIdx.x >> 6, lane = threadIdx.x & 63;
  int row = blockIdx.x * 4 + wid;
  int nrows = B * layers * L;
  float val = 0.f;
  if (row < nrows) {
    int o = row % L;
    int bl = row / L;
    int layer = bl % layers;
    int b = bl / layers;
    const float* x = ali_out + ((size_t)(b * layers + layer) * (L + 1) + o) * T;
    float s = 0.f;
    if ((T & 3) == 0) {
      int nf4 = T >> 2;
      for (int k = lane; k < nf4; k += 64) {
        float4 v = reinterpret_cast<const float4*>(x)[k];
        float base = (float)(4 * k);
        s += v.x * (base + 1.f) + v.y * (base + 2.f) +
             v.z * (base + 3.f) + v.w * (base + 4.f);
      }
    } else {
      for (int k = lane; k < T; k += 64) s += x[k] * (float)(k + 1);
    }
    s = wave_sum_f(s);
    int cnt = 0;
    for (int l = lane; l < L; l += 64)
      cnt += (ali_beg[(size_t)b * L + l] != -1) ? 1 : 0;
    cnt = wave_sum_i(cnt);
    if (lane == 0) {
      float lat = (o >= cnt) ? 0.f : (s - ali[(size_t)b * L + o]);
      val = lat * lat;
    }
  }
  if (lane == 0) ps[wid] = val;
  __syncthreads();
  if (threadIdx.x == 0) partials[blockIdx.x] = ps[0] + ps[1] + ps[2] + ps[3];
}

// ---------------------------------------------------------------------------
// Kernel D: reduce partials, compute total = layers * sum(ylen), write scalar.
// ---------------------------------------------------------------------------
__global__ __launch_bounds__(256) void kD_final(
    const float* __restrict__ partials, int nparts,
    const int* __restrict__ ali_beg, int BL, int layers, int T,
    float* __restrict__ out)
{
  __shared__ float wred[4];
  __shared__ int wcnt[4];
  int tid = threadIdx.x, w = tid >> 6;
  float s = 0.f;
  for (int k = tid; k < nparts; k += 256) s += partials[k];
  s = wave_sum_f(s);
  int c = 0;
  for (int k = tid; k < BL; k += 256) c += (ali_beg[k] != -1) ? 1 : 0;
  c = wave_sum_i(c);
  if ((tid & 63) == 0) { wred[w] = s; wcnt[w] = c; }
  __syncthreads();
  if (tid == 0) {
    float ss = wred[0] + wred[1] + wred[2] + wred[3];
    float total = (float)(wcnt[0] + wcnt[1] + wcnt[2] + wcnt[3]) * (float)layers;
    out[0] = ss / total / (float)T;
  }
}

extern "C" void kernel_launch(void* const* d_in, const int* in_sizes, int n_in,
                              void* d_out, int out_size, void* d_ws, size_t ws_size,
                              hipStream_t stream)
{
  const float* ali_out   = (const float*)d_in[0];
  const int*   ali_beg   = (const int*)d_in[1];
  // d_in[2] ali_end, d_in[3] enc_mask, d_in[6] ctc_len: unused by reference math
  const float* ctc_out   = (const float*)d_in[4];
  const int*   ctc_label = (const int*)d_in[5];

  int B = in_sizes[6];
  int L = in_sizes[1] / B;
  int T = in_sizes[3] / B;
  int V = (int)((long long)in_sizes[4] / ((long long)B * T));
  int layers = (int)((long long)in_sizes[0] / ((long long)B * (L + 1) * T));

  int N = 2 * L + 1;
  int LANES = (N + 6) / 7;           // 58
  int ROWF = LANES * 4 + 8;          // 240 floats (960 B, 16B aligned)
  int TPAD = T + 64;                 // DMA over-read pad

  // workspace layout
  float* lp = (float*)d_ws;                              // B*TPAD*ROWF floats
  float* ali = lp + (size_t)B * TPAD * ROWF;             // B*L
  float* partials = ali + (size_t)B * L;                 // gridC
  int nrows = B * layers * L;
  int gridC = (nrows + 3) / 4;
  unsigned short* offg = (unsigned short*)(partials + gridC);  // B*(T-1)*LANES

  // A: logsumexp + gather into packed rows
  size_t shA = (size_t)V * sizeof(float);
  hipLaunchKernelGGL(kA_lse_gather, dim3(B * T), dim3(256), shA, stream,
                     ctc_out, ctc_label, lp, B, T, V, L, LANES, TPAD, ROWF);

  // B: Viterbi forward + backtrace (one wave per batch item)
  size_t shB = (size_t)2 * 64 * ROWF * sizeof(float);    // 122880 B
  hipFuncSetAttribute(reinterpret_cast<const void*>(kB_viterbi),
                      hipFuncAttributeMaxDynamicSharedMemorySize, (int)shB);
  hipLaunchKernelGGL(kB_viterbi, dim3(B), dim3(64), shB, stream,
                     lp, ctc_label, offg, ali, B, T, L, TPAD, ROWF);

  // C: expected-position rows + squared residual partials
  hipLaunchKernelGGL(kC_rows, dim3(gridC), dim3(256), 0, stream,
                     ali_out, ali, ali_beg, partials, B, layers, L, T);

  // D: finalize scalar
  hipLaunchKernelGGL(kD_final, dim3(1), dim3(256), 0, stream,
                     partials, gridC, ali_beg, B * L, layers, T, (float*)d_out);
}

// Round 6
// 498.889 us; speedup vs baseline: 1.1702x; 1.1520x over previous
//
#include <hip/hip_runtime.h>
#include <hip/hip_bf16.h>
#include <math.h>

#define NEGINF (-INFINITY)

typedef float f32x4 __attribute__((ext_vector_type(4)));

__device__ __forceinline__ float wave_max_f(float m) {
#pragma unroll
  for (int d = 32; d > 0; d >>= 1) m = fmaxf(m, __shfl_xor(m, d, 64));
  return m;
}
__device__ __forceinline__ float wave_sum_f(float s) {
#pragma unroll
  for (int d = 32; d > 0; d >>= 1) s += __shfl_xor(s, d, 64);
  return s;
}
__device__ __forceinline__ int wave_sum_i(int s) {
#pragma unroll
  for (int d = 32; d > 0; d >>= 1) s += __shfl_xor(s, d, 64);
  return s;
}

// Whole-wave shift-right-by-1 via DPP (pure VALU). Lane l gets lane l-1's
// value; lane 0 gets 0 (caller overrides).
__device__ __forceinline__ float dpp_wave_shr1(float x) {
  int r = __builtin_amdgcn_mov_dpp(__float_as_int(x), 0x138, 0xf, 0xf, true);
  return __int_as_float(r);
}

// ---------------------------------------------------------------------------
// Kernel A: per (b,t) row of ctc_out[V]: logsumexp, then gather into packed
// row layout (stride ROWF=LANES*4+8 floats = 960 B):
//   row[0 .. LANES*4)  = label lps, quad s -> labels jbase(s)..+3 (clamped)
//   row[LANES*4]       = blank lp
// ---------------------------------------------------------------------------
__global__ __launch_bounds__(256) void kA_lse_gather(
    const float* __restrict__ ctc_out, const int* __restrict__ ctc_label,
    float* __restrict__ lp, int B, int T, int V, int L, int LANES,
    int TPAD, int ROWF)
{
  extern __shared__ float shrow[];  // V floats
  __shared__ float wred[4];
  int row = blockIdx.x;             // b*T + t
  int b = row / T;
  int t = row - b * T;
  int tid = threadIdx.x;
  int w = tid >> 6;
  const float* x = ctc_out + (size_t)row * V;

  float m = NEGINF;
  int nf4 = V >> 2;
  for (int k = tid; k < nf4; k += 256) {
    float4 v = reinterpret_cast<const float4*>(x)[k];
    reinterpret_cast<float4*>(shrow)[k] = v;
    m = fmaxf(m, fmaxf(fmaxf(v.x, v.y), fmaxf(v.z, v.w)));
  }
  for (int k = (nf4 << 2) + tid; k < V; k += 256) {
    float v = x[k]; shrow[k] = v; m = fmaxf(m, v);
  }
  m = wave_max_f(m);
  if ((tid & 63) == 0) wred[w] = m;
  __syncthreads();
  float bm = fmaxf(fmaxf(wred[0], wred[1]), fmaxf(wred[2], wred[3]));
  __syncthreads();

  float s = 0.f;
  for (int k = tid; k < V; k += 256) s += __expf(shrow[k] - bm);
  s = wave_sum_f(s);
  if ((tid & 63) == 0) wred[w] = s;
  __syncthreads();
  float lse = bm + __logf(wred[0] + wred[1] + wred[2] + wred[3]);

  const int* lab = ctc_label + (size_t)b * L;
  float* dst = lp + ((size_t)b * TPAD + t) * ROWF;
  int nq = LANES * 4;
  for (int idx = tid; idx < nq; idx += 256) {
    int sl = idx >> 2, q = idx & 3;
    int jb = ((7 * sl) >> 1) + 1;
    int j = jb + q; if (j > L) j = L;
    int vi = lab[j - 1];
    if ((unsigned)vi >= (unsigned)V) vi = 0;
    dst[idx] = shrow[vi] - lse;
  }
  if (tid == 0) dst[nq] = shrow[0] - lse;
}

// ---------------------------------------------------------------------------
// Kernel B: Viterbi forced alignment, one wave per batch item.
// Lane l owns states 7l..7l+6. lp staged global->LDS via global_load_lds in
// 16-row double-buffered segments (DMA for sg+1 issued at start of sg; one
// "memory"-fenced vmcnt(0) at body 12). The ENTIRE inner body's LDS traffic
// is inline asm (ds_read_b128/b32 ring + ds_write_b16 offsets) with
// hand-counted lgkmcnt(9) - the compiler sees no memory ops to legalize, so
// no conservative vmcnt(0)-per-body can appear. offrow lives in LDS
// ((T-1) x 128B rows); backtrace chases it with batched speculative reads.
// ---------------------------------------------------------------------------
__global__ __launch_bounds__(64, 1) void kB_viterbi(
    const float* __restrict__ lp, const int* __restrict__ ctc_label,
    float* __restrict__ ali, int B, int T, int L, int TPAD, int ROWF)
{
  extern __shared__ float smemf[];
  // LDS layout (byte offsets from dynamic base):
  //   buf0 @ 0       (16*ROWF*4 = 15360 B)
  //   buf1 @ 15360   (15360 B)
  //   offrow @ 30720 ((T-1) * 128 B)
  const int N = 2 * L + 1;
  const int LANES = (N + 6) / 7;
  const unsigned STGB = (unsigned)(16 * ROWF * 4);     // 15360
  const unsigned OFFROW = 2u * STGB;                   // 30720

  int b = blockIdx.x;
  int lane = threadIdx.x;
  const float* lpb = lp + (size_t)b * TPAD * ROWF;
  const int* lab = ctc_label + (size_t)b * L;
  int qlane = (lane < LANES) ? lane : (LANES - 1);
  int blkoff = LANES * 4;            // blank float-offset within row
  unsigned sbase = __builtin_amdgcn_groupstaticsize();  // 0 (no static LDS)

  int i0 = lane * 7;
  float a0v, a1v, a2v, a3v, a4v, a5v, a6v;
  int twv[7];
  int tlo[7];
  unsigned rng[7];
#pragma unroll
  for (int s = 0; s < 7; ++s) {
    int i = i0 + s;
    bool valid = (i < N);
    bool odd = (i & 1) != 0;
    int li = (i - 1) >> 1;
    int myl = (odd && valid) ? lab[li] : 0;
    int pl  = (odd && valid && i >= 3) ? lab[li - 1] : -1;
    twv[s] = ((!odd) || (i == 1) || (myl == pl)) ? 1 : 0;
    if (valid) {
      tlo[s] = (i + 1) >> 1;                 // t >= ceil(i/2)
      int thi = T - L + (i >> 1);            // t <= T-L+floor(i/2)
      rng[s] = (unsigned)(thi - tlo[s]);
    } else {
      tlo[s] = T + 2;
      rng[s] = 0u;
    }
  }

  // t=0 init (direct global reads, before any asm LDS traffic).
  {
    f32x4 q00 = reinterpret_cast<const f32x4*>(lpb)[qlane];
    float bl00 = lpb[blkoff];
    a0v = (i0 == 0) ? bl00 : NEGINF;
    a1v = NEGINF; a2v = NEGINF; a3v = NEGINF; a4v = NEGINF; a5v = NEGINF;
    a6v = NEGINF;
    if (i0 + 1 == 1) a1v = q00.x;   // only lane 0 state 1
  }

  // DMA one 16-row segment starting at global row row0 into buffer bufidx.
  int ndma = ROWF >> 4;              // 15 ops of 1KB
#define DMA_SEG(row0, bufidx)                                                 \
  {                                                                           \
    const float* gsrc_ = lpb + (size_t)(row0) * ROWF;                         \
    char* dbase_ = (char*)smemf + (unsigned)(bufidx) * STGB;                  \
    for (int kk_ = 0; kk_ < ndma; ++kk_) {                                    \
      __builtin_amdgcn_global_load_lds(                                       \
          (const unsigned int*)(gsrc_ + (size_t)kk_ * 256 + lane * 4),        \
          (unsigned int*)(dbase_ + kk_ * 1024), 16, 0, 0);                    \
    }                                                                         \
  }

  f32x4 rqA, rqB, rqC, rqD;
  float rblA, rblB, rblC, rblD;

#define RINGRD(SL, qaddr, baddr)                                              \
  asm volatile("ds_read_b128 %0, %1" : "=v"(rq##SL) : "v"(qaddr));            \
  asm volatile("ds_read_b32 %0, %1" : "=v"(rbl##SL) : "v"(baddr));

#define STEP_F(s, P0, P1, P2, OCS, ND, OD)                                    \
  {                                                                           \
    bool c01 = (P0) > (P1);                                                   \
    float m01 = c01 ? (P0) : (P1);                                            \
    bool take3 = (twv[s] == 0) && !(m01 > (P2));                              \
    float asel = take3 ? (P2) : m01;                                          \
    OD = take3 ? 2u : (c01 ? 0u : 1u);                                        \
    float lps = (((lane + (s)) & 1) ? (OCS) : blc);                           \
    ND = asel + lps;                                                          \
  }

#define STEP_S(s, P0, P1, P2, OCS, ND, OD)                                    \
  {                                                                           \
    STEP_F(s, P0, P1, P2, OCS, ND, OD)                                        \
    bool feas = (unsigned)(tt - tlo[s]) <= rng[s];                            \
    ND = feas ? ND : NEGINF;                                                  \
  }

  // One DP body. SL = ring slot letter, UL = compile-time row-in-segment.
#define BODY(SL, UL, STEPM)                                                   \
  {                                                                           \
    const int tt = tt0 + (UL);                                                \
    asm volatile("s_waitcnt lgkmcnt(9)");                                     \
    __builtin_amdgcn_sched_barrier(0);                                        \
    float blc = rbl##SL;                                                      \
    f32x4 oc = rq##SL;                                                        \
    float n0, n1, n2, n3, n4, n5, n6;                                         \
    unsigned o0, o1, o2, o3, o4, o5, o6;                                      \
    STEPM(5, a5v, a4v, a3v, oc.z, n5, o5)                                     \
    STEPM(6, a6v, a5v, a4v, oc.w, n6, o6)                                     \
    float t6n = dpp_wave_shr1(n6);                                            \
    float t5n = dpp_wave_shr1(n5);                                            \
    STEPM(0, a0v, t6, t5, oc.x, n0, o0)                                       \
    STEPM(1, a1v, a0v, t6, oc.x, n1, o1)                                      \
    STEPM(2, a2v, a1v, a0v, oc.y, n2, o2)                                     \
    STEPM(3, a3v, a2v, a1v, oc.y, n3, o3)                                     \
    STEPM(4, a4v, a3v, a2v, oc.z, n4, o4)                                     \
    unsigned pack = o0 | (o1 << 2) | (o2 << 4) | (o3 << 6) | (o4 << 8) |      \
                    (o5 << 10) | (o6 << 12);                                  \
    asm volatile("ds_write_b16 %0, %1" :: "v"(wa), "v"(pack));                \
    wa += 128;                                                                \
    if ((UL) == 12) {                                                         \
      asm volatile("s_waitcnt vmcnt(0)" ::: "memory");                        \
      __builtin_amdgcn_sched_barrier(0);                                      \
    }                                                                         \
    {                                                                         \
      unsigned qa = ((UL) < 12) ? (qcur + ((UL) + 4) * 960u)                  \
                                : (qnxt + ((UL) - 12) * 960u);                \
      unsigned ba = ((UL) < 12) ? (bcur + ((UL) + 4) * 960u)                  \
                                : (bnxt + ((UL) - 12) * 960u);                \
      RINGRD(SL, qa, ba)                                                      \
    }                                                                         \
    a0v = n0; a1v = n1; a2v = n2; a3v = n3; a4v = n4; a5v = n5; a6v = n6;     \
    t6 = (lane == 0) ? NEGINF : t6n;                                          \
    t5 = (lane == 0) ? NEGINF : t5n;                                          \
  }

  // Prologue: DMA segment 0 (rows 1..16) into buf0 and drain.
  DMA_SEG(1, 0)
  asm volatile("s_waitcnt vmcnt(0)" ::: "memory");
  __builtin_amdgcn_sched_barrier(0);

  unsigned wa = sbase + OFFROW + (unsigned)(lane * 2);
  {
    // Ring warm-up: pairs for bodies 0..3 (buf0 rows 0..3), then 3 dummy
    // writes so "ops after pair(u)" >= 9 for every body (lgkmcnt(9) exact).
    unsigned q0 = sbase + (unsigned)(qlane * 16);
    unsigned b0 = sbase + (unsigned)(blkoff * 4);
    RINGRD(A, q0 + 0u * 960u, b0 + 0u * 960u)
    RINGRD(B, q0 + 1u * 960u, b0 + 1u * 960u)
    RINGRD(C, q0 + 2u * 960u, b0 + 2u * 960u)
    RINGRD(D, q0 + 3u * 960u, b0 + 3u * 960u)
    unsigned zz = 0;
    asm volatile("ds_write_b16 %0, %1" :: "v"(wa), "v"(zz));
    asm volatile("ds_write_b16 %0, %1" :: "v"(wa), "v"(zz));
    asm volatile("ds_write_b16 %0, %1" :: "v"(wa), "v"(zz));
  }

  // Initial shifted values from t=0 state (outside hot loop).
  float t6 = __shfl_up(a6v, 1, 64);
  float t5 = __shfl_up(a5v, 1, 64);
  if (lane == 0) { t6 = NEGINF; t5 = NEGINF; }

  int NSEG = (T - 1 + 15) >> 4;
  for (int sg = 0; sg < NSEG; ++sg) {
    int tt0 = 1 + 16 * sg;
    unsigned bufc = sbase + (unsigned)(sg & 1) * STGB;
    unsigned bufn = sbase + (unsigned)((sg + 1) & 1) * STGB;
    unsigned qcur = bufc + (unsigned)(qlane * 16);
    unsigned qnxt = bufn + (unsigned)(qlane * 16);
    unsigned bcur = bufc + (unsigned)(blkoff * 4);
    unsigned bnxt = bufn + (unsigned)(blkoff * 4);
    if (sg + 1 < NSEG) { DMA_SEG(tt0 + 16, ((sg + 1) & 1)) }
    int rem = T - tt0;   // bodies remaining (>=16 except last segment)
    bool fast = (rem >= 16) && (tt0 >= L) && (tt0 + 15 <= T - L);
    if (fast) {
      BODY(A, 0, STEP_F)  BODY(B, 1, STEP_F)  BODY(C, 2, STEP_F)
      BODY(D, 3, STEP_F)  BODY(A, 4, STEP_F)  BODY(B, 5, STEP_F)
      BODY(C, 6, STEP_F)  BODY(D, 7, STEP_F)  BODY(A, 8, STEP_F)
      BODY(B, 9, STEP_F)  BODY(C, 10, STEP_F) BODY(D, 11, STEP_F)
      BODY(A, 12, STEP_F) BODY(B, 13, STEP_F) BODY(C, 14, STEP_F)
      BODY(D, 15, STEP_F)
    } else {
      if (0 < rem)  { BODY(A, 0, STEP_S) }
      if (1 < rem)  { BODY(B, 1, STEP_S) }
      if (2 < rem)  { BODY(C, 2, STEP_S) }
      if (3 < rem)  { BODY(D, 3, STEP_S) }
      if (4 < rem)  { BODY(A, 4, STEP_S) }
      if (5 < rem)  { BODY(B, 5, STEP_S) }
      if (6 < rem)  { BODY(C, 6, STEP_S) }
      if (7 < rem)  { BODY(D, 7, STEP_S) }
      if (8 < rem)  { BODY(A, 8, STEP_S) }
      if (9 < rem)  { BODY(B, 9, STEP_S) }
      if (10 < rem) { BODY(C, 10, STEP_S) }
      if (11 < rem) { BODY(D, 11, STEP_S) }
      if (12 < rem) { BODY(A, 12, STEP_S) }
      if (13 < rem) { BODY(B, 13, STEP_S) }
      if (14 < rem) { BODY(C, 14, STEP_S) }
      if (15 < rem) { BODY(D, 15, STEP_S) }
    }
  }
#undef BODY
#undef STEP_S
#undef STEP_F
#undef RINGRD
#undef DMA_SEG

  // Drain everything before compiler-visible LDS reads (backtrace).
  asm volatile("s_waitcnt vmcnt(0) lgkmcnt(0)" ::: "memory");
  __builtin_amdgcn_sched_barrier(0);

  // Final-state values (state i -> lane i/7, slot i%7).
  int iN1 = N - 1, iN2 = N - 2;
  auto pick = [&](int sIdx) {
    float r = a0v;
    r = (sIdx == 1) ? a1v : r;
    r = (sIdx == 2) ? a2v : r;
    r = (sIdx == 3) ? a3v : r;
    r = (sIdx == 4) ? a4v : r;
    r = (sIdx == 5) ? a5v : r;
    r = (sIdx == 6) ? a6v : r;
    return r;
  };
  float vlast = __shfl(pick(iN1 % 7), iN1 / 7, 64);
  float vprev = __shfl(pick(iN2 % 7), iN2 / 7, 64);
  bool use_last = vlast > vprev;
  int pre = use_last ? iN1 : iN2;

  float al[4] = {0.f, 0.f, 0.f, 0.f};
  {
    int lbl = L - 1; int rr = lbl >> 6, ln = lbl & 63;
#pragma unroll
    for (int r = 0; r < 4; ++r)
      if (!use_last && rr == r && lane == ln) al[r] = (float)T;
  }

  // Backtrace from LDS offrow (rows of 64 u16; entry g of row t-1).
  const unsigned short* offrow =
      (const unsigned short*)((char*)smemf + OFFROW);
  int t = T - 1;
  int g = pre / 7, mm = pre - g * 7;
  while (t >= 1) {
    int K = (t < 7) ? t : 7;
    int pcur = g * 7 + mm;
    int gmax = g;
    unsigned short w0v = offrow[(size_t)(t - 1) * 64 + g];
    unsigned short cw[7][3];
    int gmn[7];
#pragma unroll
    for (int j = 1; j < 7; ++j) {
      if (j < K) {
        int lo = pcur - 2 * j; if (lo < 0) lo = 0;
        int gm = lo / 7;
        gmn[j] = gm;
#pragma unroll
        for (int r = 0; r < 3; ++r) {
          int gg = gm + r; if (gg > gmax) gg = gmax;
          cw[j][r] = offrow[(size_t)(t - 1 - j) * 64 + gg];
        }
      }
    }
#pragma unroll
    for (int j = 0; j < 7; ++j) {
      if (j < K) {
        unsigned w;
        if (j == 0) {
          w = w0v;
        } else {
          int gi = g - gmn[j];
          unsigned wva = cw[j][0], wvb = cw[j][1], wvc = cw[j][2];
          w = (gi == 0) ? wva : ((gi == 1) ? wvb : wvc);
        }
        unsigned off = (w >> (2 * mm)) & 3u;
        mm -= (int)off;
        bool bor = mm < 0;
        g = bor ? (g - 1) : g;
        mm = bor ? (mm + 7) : mm;
        int cur = g * 7 + mm;
        if (cur & 1) {
          int lbl = cur >> 1;
          int rr = lbl >> 6, ln = lbl & 63;
#pragma unroll
          for (int r = 0; r < 4; ++r)
            if (rr == r && lane == ln) al[r] = (float)(t - j);
        }
      }
    }
    t -= K;
  }

#pragma unroll
  for (int r = 0; r < 4; ++r) {
    int l = lane + 64 * r;
    if (l < L) ali[(size_t)b * L + l] = al[r];
  }
}

// ---------------------------------------------------------------------------
// Kernel C: one wave per (b,layer,o<L) row: dot(ali_out_row, pos) - ali,
// masked, squared; 4 rows/block -> per-block partial sum.
// ---------------------------------------------------------------------------
__global__ __launch_bounds__(256) void kC_rows(
    const float* __restrict__ ali_out, const float* __restrict__ ali,
    const int* __restrict__ ali_beg, float* __restrict__ partials,
    int B, int layers, int L, int T)
{
  __shared__ float ps[4];
  int wid = threadIdx.x >> 6, lane = threadIdx.x & 63;
  int row = blockIdx.x * 4 + wid;
  int nrows = B * layers * L;
  float val = 0.f;
  if (row < nrows) {
    int o = row % L;
    int bl = row / L;
    int layer = bl % layers;
    int b = bl / layers;
    const float* x = ali_out + ((size_t)(b * layers + layer) * (L + 1) + o) * T;
    float s = 0.f;
    if ((T & 3) == 0) {
      int nf4 = T >> 2;
      for (int k = lane; k < nf4; k += 64) {
        float4 v = reinterpret_cast<const float4*>(x)[k];
        float base = (float)(4 * k);
        s += v.x * (base + 1.f) + v.y * (base + 2.f) +
             v.z * (base + 3.f) + v.w * (base + 4.f);
      }
    } else {
      for (int k = lane; k < T; k += 64) s += x[k] * (float)(k + 1);
    }
    s = wave_sum_f(s);
    int cnt = 0;
    for (int l = lane; l < L; l += 64)
      cnt += (ali_beg[(size_t)b * L + l] != -1) ? 1 : 0;
    cnt = wave_sum_i(cnt);
    if (lane == 0) {
      float lat = (o >= cnt) ? 0.f : (s - ali[(size_t)b * L + o]);
      val = lat * lat;
    }
  }
  if (lane == 0) ps[wid] = val;
  __syncthreads();
  if (threadIdx.x == 0) partials[blockIdx.x] = ps[0] + ps[1] + ps[2] + ps[3];
}

// ---------------------------------------------------------------------------
// Kernel D: reduce partials, compute total = layers * sum(ylen), write scalar.
// ---------------------------------------------------------------------------
__global__ __launch_bounds__(256) void kD_final(
    const float* __restrict__ partials, int nparts,
    const int* __restrict__ ali_beg, int BL, int layers, int T,
    float* __restrict__ out)
{
  __shared__ float wred[4];
  __shared__ int wcnt[4];
  int tid = threadIdx.x, w = tid >> 6;
  float s = 0.f;
  for (int k = tid; k < nparts; k += 256) s += partials[k];
  s = wave_sum_f(s);
  int c = 0;
  for (int k = tid; k < BL; k += 256) c += (ali_beg[k] != -1) ? 1 : 0;
  c = wave_sum_i(c);
  if ((tid & 63) == 0) { wred[w] = s; wcnt[w] = c; }
  __syncthreads();
  if (tid == 0) {
    float ss = wred[0] + wred[1] + wred[2] + wred[3];
    float total = (float)(wcnt[0] + wcnt[1] + wcnt[2] + wcnt[3]) * (float)layers;
    out[0] = ss / total / (float)T;
  }
}

extern "C" void kernel_launch(void* const* d_in, const int* in_sizes, int n_in,
                              void* d_out, int out_size, void* d_ws, size_t ws_size,
                              hipStream_t stream)
{
  const float* ali_out   = (const float*)d_in[0];
  const int*   ali_beg   = (const int*)d_in[1];
  // d_in[2] ali_end, d_in[3] enc_mask, d_in[6] ctc_len: unused by reference math
  const float* ctc_out   = (const float*)d_in[4];
  const int*   ctc_label = (const int*)d_in[5];

  int B = in_sizes[6];
  int L = in_sizes[1] / B;
  int T = in_sizes[3] / B;
  int V = (int)((long long)in_sizes[4] / ((long long)B * T));
  int layers = (int)((long long)in_sizes[0] / ((long long)B * (L + 1) * T));

  int N = 2 * L + 1;
  int LANES = (N + 6) / 7;           // 58
  int ROWF = LANES * 4 + 8;          // 240 floats (960 B)
  int TPAD = T + 64;                 // DMA over-read pad

  // workspace layout
  float* lp = (float*)d_ws;                              // B*TPAD*ROWF floats
  float* ali = lp + (size_t)B * TPAD * ROWF;             // B*L
  float* partials = ali + (size_t)B * L;                 // gridC
  int nrows = B * layers * L;
  int gridC = (nrows + 3) / 4;

  // A: logsumexp + gather into packed rows
  size_t shA = (size_t)V * sizeof(float);
  hipLaunchKernelGGL(kA_lse_gather, dim3(B * T), dim3(256), shA, stream,
                     ctc_out, ctc_label, lp, B, T, V, L, LANES, TPAD, ROWF);

  // B: Viterbi forward + backtrace (one wave per batch item)
  // LDS: 2 staging buffers (2*16*ROWF*4 B) + offrow ((T-1)*128 B)
  size_t shB = (size_t)2 * 16 * ROWF * sizeof(float) + (size_t)(T - 1) * 128;
  hipFuncSetAttribute(reinterpret_cast<const void*>(kB_viterbi),
                      hipFuncAttributeMaxDynamicSharedMemorySize, (int)shB);
  hipLaunchKernelGGL(kB_viterbi, dim3(B), dim3(64), shB, stream,
                     lp, ctc_label, ali, B, T, L, TPAD, ROWF);

  // C: expected-position rows + squared residual partials
  hipLaunchKernelGGL(kC_rows, dim3(gridC), dim3(256), 0, stream,
                     ali_out, ali, ali_beg, partials, B, layers, L, T);

  // D: finalize scalar
  hipLaunchKernelGGL(kD_final, dim3(1), dim3(256), 0, stream,
                     partials, gridC, ali_beg, B * L, layers, T, (float*)d_out);
}